// Round 5
// baseline (221.634 us; speedup 1.0000x reference)
//
#include <hip/hip_runtime.h>

#define VOCAB 1000000
#define NUM_TABLES 10
#define OUT_SIZE 26
#define BUCKET_BITS 12
#define BPB 4096                // bins per bucket
#define NBUCKETS 245            // ceil(1e6/4096)
#define CHUNK 4096              // indices per scatter block
#define MAXSRC 1024             // max scatter blocks supported by fast path
#define NGROUPS (VOCAB / 4)     // 250000 4-row groups
#define RBLK ((NGROUPS + 255) / 256)   // 977 reduce blocks
#define PSTRIDE 1024            // partials stride per series

// ---------------- fast path ----------------

// Partition indices by bucket (idx>>12) into each block's PRIVATE dense region.
// No global atomics; pass-2 permutation staged in LDS, dumped coalesced.
__global__ void __launch_bounds__(256) scatter_kernel(
    const int* __restrict__ idx, int n,
    unsigned short* __restrict__ scat,   // [nsrc][CHUNK] u16 (bin within bucket)
    unsigned int* __restrict__ gs32)     // [NBUCKETS][MAXSRC]: start | count<<16
{
    __shared__ unsigned int lcount[256];
    __shared__ unsigned int sc[256];
    __shared__ unsigned short stage[CHUNK];   // 8 KB
    const int tid = threadIdx.x;
    lcount[tid] = 0u;
    __syncthreads();

    const int4* idx4 = (const int4*)idx;
    const int n4 = n >> 2;
    const int base4 = blockIdx.x * (CHUNK / 4);
    int4 q[4];
    bool val[4];
    unsigned rank[16];
    unsigned bkt[16];
#pragma unroll
    for (int j = 0; j < 4; ++j) {
        int i4 = base4 + j * 256 + tid;
        val[j] = (i4 < n4);
        if (val[j]) q[j] = idx4[i4];
    }
    // pass 1: per-element rank within (block, bucket)
#pragma unroll
    for (int j = 0; j < 4; ++j) {
        if (val[j]) {
            unsigned v[4] = {(unsigned)q[j].x, (unsigned)q[j].y, (unsigned)q[j].z, (unsigned)q[j].w};
#pragma unroll
            for (int e = 0; e < 4; ++e) {
                bkt[j * 4 + e] = v[e] >> BUCKET_BITS;
                rank[j * 4 + e] = atomicAdd(&lcount[bkt[j * 4 + e]], 1u);
            }
        }
    }
    // tail (n%4): last block, thread 0 (dead code for n=4M)
    unsigned trank[3], tbkt[3];
    int tcnt = 0;
    if (blockIdx.x == gridDim.x - 1 && tid == 0) {
        for (int i = n4 * 4; i < n; ++i) {
            unsigned u = (unsigned)idx[i];
            tbkt[tcnt] = u >> BUCKET_BITS;
            trank[tcnt] = atomicAdd(&lcount[tbkt[tcnt]], 1u);
            ++tcnt;
        }
    }
    __syncthreads();
    // inclusive scan over 245 bucket counts (padded to 256)
    unsigned cnt = (tid < NBUCKETS) ? lcount[tid] : 0u;
    sc[tid] = cnt;
    __syncthreads();
#pragma unroll
    for (int off = 1; off < 256; off <<= 1) {
        unsigned v = sc[tid];
        unsigned a = (tid >= off) ? sc[tid - off] : 0u;
        __syncthreads();
        sc[tid] = v + a;
        __syncthreads();
    }
    unsigned excl = sc[tid] - cnt;
    if (tid < NBUCKETS) gs32[tid * MAXSRC + blockIdx.x] = excl | (cnt << 16);
    lcount[tid] = excl;   // reuse as per-bucket base
    __syncthreads();
    // pass 2: scatter into LDS stage (unique positions, no atomics)
#pragma unroll
    for (int j = 0; j < 4; ++j) {
        if (val[j]) {
            unsigned v[4] = {(unsigned)q[j].x, (unsigned)q[j].y, (unsigned)q[j].z, (unsigned)q[j].w};
#pragma unroll
            for (int e = 0; e < 4; ++e) {
                unsigned k = j * 4 + e;
                stage[lcount[bkt[k]] + rank[k]] = (unsigned short)(v[e] & (BPB - 1));
            }
        }
    }
    if (blockIdx.x == gridDim.x - 1 && tid == 0) {
        for (int i = 0; i < tcnt; ++i) {
            unsigned u = (unsigned)idx[n4 * 4 + i];
            stage[lcount[tbkt[i]] + trank[i]] = (unsigned short)(u & (BPB - 1));
        }
    }
    __syncthreads();
    // coalesced dump: 4096 u16 = 512 uint4
    uint4* dst = (uint4*)(scat + (size_t)blockIdx.x * CHUNK);
    const uint4* src = (const uint4*)stage;
#pragma unroll
    for (int j = 0; j < 2; ++j) dst[j * 256 + tid] = src[j * 256 + tid];
}

// 2 blocks per bucket (2/CU): each handles half the sources, writes a u16
// partial hist (linear bin layout). No global atomics, coalesced writes.
__global__ void __launch_bounds__(512) bucket_hist_kernel(
    const unsigned short* __restrict__ scat,
    const unsigned int* __restrict__ gs32, int nsrc,
    unsigned short* __restrict__ h0,
    unsigned short* __restrict__ h1)
{
    __shared__ unsigned int h[BPB];   // 16 KB
    const int b = blockIdx.x >> 1;
    const int qh = blockIdx.x & 1;
    const int tid = threadIdx.x;
    const int half = (nsrc + 1) >> 1;
    for (int i = tid; i < BPB; i += 512) h[i] = 0u;
    __syncthreads();
    const int s0 = qh * half;
    const int scount = min(half, nsrc - s0);
    for (int t = tid; t < scount; t += 512) {
        const int src = s0 + t;
        unsigned g32 = gs32[b * MAXSRC + src];
        unsigned s = g32 & 0xffffu, c = g32 >> 16;
        const unsigned short* p = scat + (size_t)src * CHUNK + s;
        unsigned k = 0;
        for (; k + 4 <= c; k += 4) {
            unsigned short a0 = p[k], a1 = p[k + 1], a2 = p[k + 2], a3 = p[k + 3];
            atomicAdd(&h[a0], 1u);
            atomicAdd(&h[a1], 1u);
            atomicAdd(&h[a2], 1u);
            atomicAdd(&h[a3], 1u);
        }
        for (; k < c; ++k) atomicAdd(&h[p[k]], 1u);
    }
    __syncthreads();
    // pack u32 -> u16, coalesced uint4 writes (8 bins / thread)
    unsigned short* dst = (qh ? h1 : h0) + (size_t)b * BPB;
    const int base = tid * 8;
    uint4 o;
    o.x = h[base + 0] | (h[base + 1] << 16);
    o.y = h[base + 2] | (h[base + 3] << 16);
    o.z = h[base + 4] | (h[base + 5] << 16);
    o.w = h[base + 6] | (h[base + 7] << 16);
    ((uint4*)dst)[tid] = o;
}

__device__ inline float wave_reduce(float v) {
#pragma unroll
    for (int o = 32; o > 0; o >>= 1) v += __shfl_down(v, o, 64);
    return v;
}

// One thread per 4-row group, ALL 10 tables: 30 independent float4 W loads
// + 2 uint2 hist loads. Hist read once total (4 MB), max ILP on W stream.
__global__ void __launch_bounds__(256) reduce_kernel(
    const float* __restrict__ W,
    const unsigned short* __restrict__ h0,
    const unsigned short* __restrict__ h1,
    float* __restrict__ partials)
{
    const int g = blockIdx.x * 256 + (int)threadIdx.x;
    float acc[NUM_TABLES][3];
#pragma unroll
    for (int t = 0; t < NUM_TABLES; ++t) { acc[t][0] = 0.f; acc[t][1] = 0.f; acc[t][2] = 0.f; }
    if (g < NGROUPS) {
        uint2 pa = ((const uint2*)h0)[g];
        uint2 pb = ((const uint2*)h1)[g];
        float c0 = (float)((pa.x & 0xffffu) + (pb.x & 0xffffu));
        float c1 = (float)((pa.x >> 16) + (pb.x >> 16));
        float c2 = (float)((pa.y & 0xffffu) + (pb.y & 0xffffu));
        float c3 = (float)((pa.y >> 16) + (pb.y >> 16));
        const size_t w4base = 3 * (size_t)g;
#pragma unroll
        for (int t = 0; t < NUM_TABLES; ++t) {
            const float4* W4 = ((const float4*)W) + (size_t)t * 750000 + w4base;
            float4 w0 = W4[0];
            float4 w1 = W4[1];
            float4 w2 = W4[2];
            acc[t][0] = c0 * w0.x + c1 * w0.w + c2 * w1.z + c3 * w2.y;
            acc[t][1] = c0 * w0.y + c1 * w1.x + c2 * w1.w + c3 * w2.z;
            acc[t][2] = c0 * w0.z + c1 * w1.y + c2 * w2.x + c3 * w2.w;
        }
    }
    __shared__ float sf[30 * 4];
    const int wave = threadIdx.x >> 6, lane = threadIdx.x & 63;
#pragma unroll
    for (int t = 0; t < NUM_TABLES; ++t)
#pragma unroll
        for (int d = 0; d < 3; ++d) {
            float v = wave_reduce(acc[t][d]);
            if (lane == 0) sf[(t * 3 + d) * 4 + wave] = v;
        }
    __syncthreads();
    if (threadIdx.x < 30) {
        const float* p = &sf[threadIdx.x * 4];
        partials[threadIdx.x * PSTRIDE + blockIdx.x] = p[0] + p[1] + p[2] + p[3];
    }
}

__global__ void __launch_bounds__(1024) final_kernel(const float* __restrict__ partials,
                                                     int nblk, float* __restrict__ out) {
    __shared__ float ts[32];
    const int tid = threadIdx.x;
    const int srs = tid >> 5;      // 0..31, use <30
    const int j = tid & 31;
    float v = 0.f;
    if (srs < 30) {
        const float* p = partials + (size_t)srs * PSTRIDE;
        for (int k = j; k < nblk; k += 32) v += p[k];
    }
#pragma unroll
    for (int off = 16; off > 0; off >>= 1) v += __shfl_down(v, off, 32);
    if (j == 0 && srs < 30) ts[srs] = v;
    __syncthreads();
    if (tid < OUT_SIZE) {
        float r;
        if (tid < 15) r = ts[tid];
        else if (tid == 15) r = ts[15] + ts[16] + ts[17];
        else if (tid == 16) r = ts[18] + ts[19] + ts[20];
        else r = ts[tid + 4];
        out[tid] = r;
    }
}

// ---------------- fallback path (R1, proven) ----------------

__global__ void zero_kernel_fb(unsigned int* __restrict__ hist, float* __restrict__ out) {
    int i = blockIdx.x * blockDim.x + threadIdx.x;
    int n4 = VOCAB / 4;
    if (i < n4) ((uint4*)hist)[i] = make_uint4(0u, 0u, 0u, 0u);
    if (i < OUT_SIZE) out[i] = 0.0f;
}

__global__ void hist_kernel_fb(const int* __restrict__ idx, unsigned int* __restrict__ hist, int n) {
    int i = blockIdx.x * blockDim.x + threadIdx.x;
    int i4 = i * 4;
    if (i4 + 3 < n) {
        int4 v = ((const int4*)idx)[i];
        atomicAdd(&hist[v.x], 1u);
        atomicAdd(&hist[v.y], 1u);
        atomicAdd(&hist[v.z], 1u);
        atomicAdd(&hist[v.w], 1u);
    } else {
        for (int j = i4; j < n; ++j) atomicAdd(&hist[idx[j]], 1u);
    }
}

__global__ void __launch_bounds__(256) reduce_kernel_fb(const float* __restrict__ W,
                                                        const unsigned int* __restrict__ hist,
                                                        float* __restrict__ out) {
    const int t = blockIdx.x / 64;
    const int b = blockIdx.x % 64;
    const float4* __restrict__ W4 = (const float4*)(W + (size_t)t * VOCAB * 3);
    const uint4* __restrict__ h4 = (const uint4*)hist;
    float a0 = 0.f, a1 = 0.f, a2 = 0.f;
    const int stride = 64 * 256;
    for (int g = b * 256 + (int)threadIdx.x; g < NGROUPS; g += stride) {
        uint4 c4 = h4[g];
        float4 w0 = W4[3 * g + 0];
        float4 w1 = W4[3 * g + 1];
        float4 w2 = W4[3 * g + 2];
        float c0 = (float)c4.x, c1 = (float)c4.y, c2 = (float)c4.z, c3 = (float)c4.w;
        a0 += c0 * w0.x + c1 * w0.w + c2 * w1.z + c3 * w2.y;
        a1 += c0 * w0.y + c1 * w1.x + c2 * w1.w + c3 * w2.z;
        a2 += c0 * w0.z + c1 * w1.y + c2 * w2.x + c3 * w2.w;
    }
    a0 = wave_reduce(a0);
    a1 = wave_reduce(a1);
    a2 = wave_reduce(a2);
    __shared__ float s[3][4];
    int wave = threadIdx.x >> 6;
    int lane = threadIdx.x & 63;
    if (lane == 0) { s[0][wave] = a0; s[1][wave] = a1; s[2][wave] = a2; }
    __syncthreads();
    if (threadIdx.x == 0) {
        float r0 = s[0][0] + s[0][1] + s[0][2] + s[0][3];
        float r1 = s[1][0] + s[1][1] + s[1][2] + s[1][3];
        float r2 = s[2][0] + s[2][1] + s[2][2] + s[2][3];
        if (t == 5) atomicAdd(&out[15], r0 + r1 + r2);
        else if (t == 6) atomicAdd(&out[16], r0 + r1 + r2);
        else {
            int base = (t < 5) ? t * 3 : 17 + (t - 7) * 3;
            atomicAdd(&out[base + 0], r0);
            atomicAdd(&out[base + 1], r1);
            atomicAdd(&out[base + 2], r2);
        }
    }
}

// ---------------- launch ----------------

extern "C" void kernel_launch(void* const* d_in, const int* in_sizes, int n_in,
                              void* d_out, int out_size, void* d_ws, size_t ws_size,
                              hipStream_t stream) {
    const int* eb_input = (const int*)d_in[0];
    // d_in[1] (eb_offset) irrelevant: sum over all bags == sum over all indices.
    const float* W = (const float*)d_in[2];
    float* out = (float*)d_out;
    int n_idx = in_sizes[0];

    const int nsrc = (n_idx + CHUNK - 1) / CHUNK;
    const size_t scat_bytes = (size_t)MAXSRC * CHUNK * 2;        // 8,388,608
    const size_t gs_off = scat_bytes;
    const size_t gs_bytes = (size_t)NBUCKETS * MAXSRC * 4;       // 1,003,520
    const size_t h0_off = gs_off + gs_bytes;
    const size_t hpart_bytes = (size_t)NBUCKETS * BPB * 2;       // 2,007,040
    const size_t h1_off = h0_off + hpart_bytes;
    const size_t part_off = (h1_off + hpart_bytes + 255) & ~(size_t)255;
    const size_t need = part_off + (size_t)30 * PSTRIDE * 4;     // ~13.6 MB

    if (nsrc <= MAXSRC && ws_size >= need) {
        unsigned short* scat = (unsigned short*)d_ws;
        unsigned int* gs32 = (unsigned int*)((char*)d_ws + gs_off);
        unsigned short* h0 = (unsigned short*)((char*)d_ws + h0_off);
        unsigned short* h1 = (unsigned short*)((char*)d_ws + h1_off);
        float* partials = (float*)((char*)d_ws + part_off);

        scatter_kernel<<<nsrc, 256, 0, stream>>>(eb_input, n_idx, scat, gs32);
        bucket_hist_kernel<<<NBUCKETS * 2, 512, 0, stream>>>(scat, gs32, nsrc, h0, h1);
        reduce_kernel<<<RBLK, 256, 0, stream>>>(W, h0, h1, partials);
        final_kernel<<<1, 1024, 0, stream>>>(partials, RBLK, out);
    } else {
        unsigned int* hist = (unsigned int*)d_ws;
        int zblocks = (VOCAB / 4 + 255) / 256;
        zero_kernel_fb<<<zblocks, 256, 0, stream>>>(hist, out);
        int hthreads = (n_idx + 3) / 4;
        int hblocks = (hthreads + 255) / 256;
        hist_kernel_fb<<<hblocks, 256, 0, stream>>>(eb_input, hist, n_idx);
        reduce_kernel_fb<<<NUM_TABLES * 64, 256, 0, stream>>>(W, hist, out);
    }
}

// Round 6
// 216.798 us; speedup vs baseline: 1.0223x; 1.0223x over previous
//
#include <hip/hip_runtime.h>

#define VOCAB 1000000
#define NUM_TABLES 10
#define OUT_SIZE 26
#define BUCKET_BITS 12
#define BPB 4096                // bins per bucket
#define NBUCKETS 245            // ceil(1e6/4096)
#define CHUNK 4096              // indices per scatter block
#define MAXSRC 1024             // max scatter blocks supported by fast path
#define NGROUPS (VOCAB / 4)     // 250000 4-row groups
#define RBLK_HALF 512           // reduce blocks per 5-table half
#define PSTRIDE 1024            // partials stride per series

// ---------------- fast path ----------------

// Partition indices by bucket (idx>>12) into each block's PRIVATE dense region.
// No global atomics; pass-2 permutation staged in LDS, dumped coalesced.
__global__ void __launch_bounds__(256) scatter_kernel(
    const int* __restrict__ idx, int n,
    unsigned short* __restrict__ scat,   // [nsrc][CHUNK] u16 (bin within bucket)
    unsigned int* __restrict__ gs32)     // [NBUCKETS][MAXSRC]: start | count<<16
{
    __shared__ unsigned int lcount[256];
    __shared__ unsigned int sc[256];
    __shared__ unsigned short stage[CHUNK];   // 8 KB
    const int tid = threadIdx.x;
    lcount[tid] = 0u;
    __syncthreads();

    const int4* idx4 = (const int4*)idx;
    const int n4 = n >> 2;
    const int base4 = blockIdx.x * (CHUNK / 4);
    int4 q[4];
    bool val[4];
    unsigned rank[16];
    unsigned bkt[16];
#pragma unroll
    for (int j = 0; j < 4; ++j) {
        int i4 = base4 + j * 256 + tid;
        val[j] = (i4 < n4);
        if (val[j]) q[j] = idx4[i4];
    }
    // pass 1: per-element rank within (block, bucket)
#pragma unroll
    for (int j = 0; j < 4; ++j) {
        if (val[j]) {
            unsigned v[4] = {(unsigned)q[j].x, (unsigned)q[j].y, (unsigned)q[j].z, (unsigned)q[j].w};
#pragma unroll
            for (int e = 0; e < 4; ++e) {
                bkt[j * 4 + e] = v[e] >> BUCKET_BITS;
                rank[j * 4 + e] = atomicAdd(&lcount[bkt[j * 4 + e]], 1u);
            }
        }
    }
    // tail (n%4): last block, thread 0 (dead code for n=4M)
    unsigned trank[3], tbkt[3];
    int tcnt = 0;
    if (blockIdx.x == gridDim.x - 1 && tid == 0) {
        for (int i = n4 * 4; i < n; ++i) {
            unsigned u = (unsigned)idx[i];
            tbkt[tcnt] = u >> BUCKET_BITS;
            trank[tcnt] = atomicAdd(&lcount[tbkt[tcnt]], 1u);
            ++tcnt;
        }
    }
    __syncthreads();
    // inclusive scan over 245 bucket counts (padded to 256)
    unsigned cnt = (tid < NBUCKETS) ? lcount[tid] : 0u;
    sc[tid] = cnt;
    __syncthreads();
#pragma unroll
    for (int off = 1; off < 256; off <<= 1) {
        unsigned v = sc[tid];
        unsigned a = (tid >= off) ? sc[tid - off] : 0u;
        __syncthreads();
        sc[tid] = v + a;
        __syncthreads();
    }
    unsigned excl = sc[tid] - cnt;
    if (tid < NBUCKETS) gs32[tid * MAXSRC + blockIdx.x] = excl | (cnt << 16);
    lcount[tid] = excl;   // reuse as per-bucket base
    __syncthreads();
    // pass 2: scatter into LDS stage (unique positions, no atomics)
#pragma unroll
    for (int j = 0; j < 4; ++j) {
        if (val[j]) {
            unsigned v[4] = {(unsigned)q[j].x, (unsigned)q[j].y, (unsigned)q[j].z, (unsigned)q[j].w};
#pragma unroll
            for (int e = 0; e < 4; ++e) {
                unsigned k = j * 4 + e;
                stage[lcount[bkt[k]] + rank[k]] = (unsigned short)(v[e] & (BPB - 1));
            }
        }
    }
    if (blockIdx.x == gridDim.x - 1 && tid == 0) {
        for (int i = 0; i < tcnt; ++i) {
            unsigned u = (unsigned)idx[n4 * 4 + i];
            stage[lcount[tbkt[i]] + trank[i]] = (unsigned short)(u & (BPB - 1));
        }
    }
    __syncthreads();
    // coalesced dump: 4096 u16 = 512 uint4
    uint4* dst = (uint4*)(scat + (size_t)blockIdx.x * CHUNK);
    const uint4* src = (const uint4*)stage;
#pragma unroll
    for (int j = 0; j < 2; ++j) dst[j * 256 + tid] = src[j * 256 + tid];
}

// 2 blocks per bucket: each handles half the sources, writes a u16
// partial hist (linear bin layout). No global atomics, coalesced writes.
__global__ void __launch_bounds__(512) bucket_hist_kernel(
    const unsigned short* __restrict__ scat,
    const unsigned int* __restrict__ gs32, int nsrc,
    unsigned short* __restrict__ h0,
    unsigned short* __restrict__ h1)
{
    __shared__ unsigned int h[BPB];   // 16 KB
    const int b = blockIdx.x >> 1;
    const int qh = blockIdx.x & 1;
    const int tid = threadIdx.x;
    const int half = (nsrc + 1) >> 1;
    for (int i = tid; i < BPB; i += 512) h[i] = 0u;
    __syncthreads();
    const int s0 = qh * half;
    const int scount = min(half, nsrc - s0);
    for (int t = tid; t < scount; t += 512) {
        const int src = s0 + t;
        unsigned g32 = gs32[b * MAXSRC + src];
        unsigned s = g32 & 0xffffu, c = g32 >> 16;
        const unsigned short* p = scat + (size_t)src * CHUNK + s;
        unsigned k = 0;
        for (; k + 4 <= c; k += 4) {
            unsigned short a0 = p[k], a1 = p[k + 1], a2 = p[k + 2], a3 = p[k + 3];
            atomicAdd(&h[a0], 1u);
            atomicAdd(&h[a1], 1u);
            atomicAdd(&h[a2], 1u);
            atomicAdd(&h[a3], 1u);
        }
        for (; k < c; ++k) atomicAdd(&h[p[k]], 1u);
    }
    __syncthreads();
    // pack u32 -> u16, coalesced uint4 writes (8 bins / thread)
    unsigned short* dst = (qh ? h1 : h0) + (size_t)b * BPB;
    const int base = tid * 8;
    uint4 o;
    o.x = h[base + 0] | (h[base + 1] << 16);
    o.y = h[base + 2] | (h[base + 3] << 16);
    o.z = h[base + 4] | (h[base + 5] << 16);
    o.w = h[base + 6] | (h[base + 7] << 16);
    ((uint4*)dst)[tid] = o;
}

__device__ inline float wave_reduce(float v) {
#pragma unroll
    for (int o = 32; o > 0; o >>= 1) v += __shfl_down(v, o, 64);
    return v;
}

// 5-table fused streaming reduce, 2 sub-grids of 512 blocks.
// Per iter: 2 uint2 hist loads + 15 independent float4 W loads (~95 VGPRs).
__global__ void __launch_bounds__(256) reduce_kernel(
    const float* __restrict__ W,
    const unsigned short* __restrict__ h0,
    const unsigned short* __restrict__ h1,
    float* __restrict__ partials)
{
    const int half = blockIdx.x >> 9;        // 0 or 1
    const int b = blockIdx.x & (RBLK_HALF - 1);
    const int tbase = half * 5;
    float acc[5][3];
#pragma unroll
    for (int t = 0; t < 5; ++t) { acc[t][0] = 0.f; acc[t][1] = 0.f; acc[t][2] = 0.f; }
    const int stride = RBLK_HALF * 256;
    for (int g = b * 256 + (int)threadIdx.x; g < NGROUPS; g += stride) {
        uint2 pa = ((const uint2*)h0)[g];
        uint2 pb = ((const uint2*)h1)[g];
        float c0 = (float)((pa.x & 0xffffu) + (pb.x & 0xffffu));
        float c1 = (float)((pa.x >> 16) + (pb.x >> 16));
        float c2 = (float)((pa.y & 0xffffu) + (pb.y & 0xffffu));
        float c3 = (float)((pa.y >> 16) + (pb.y >> 16));
        const size_t w4base = 3 * (size_t)g;
#pragma unroll
        for (int t = 0; t < 5; ++t) {
            const float4* W4 = ((const float4*)W) + (size_t)(tbase + t) * 750000 + w4base;
            float4 w0 = W4[0];
            float4 w1 = W4[1];
            float4 w2 = W4[2];
            acc[t][0] += c0 * w0.x + c1 * w0.w + c2 * w1.z + c3 * w2.y;
            acc[t][1] += c0 * w0.y + c1 * w1.x + c2 * w1.w + c3 * w2.z;
            acc[t][2] += c0 * w0.z + c1 * w1.y + c2 * w2.x + c3 * w2.w;
        }
    }
    __shared__ float sf[15 * 4];
    const int wave = threadIdx.x >> 6, lane = threadIdx.x & 63;
#pragma unroll
    for (int t = 0; t < 5; ++t)
#pragma unroll
        for (int d = 0; d < 3; ++d) {
            float v = wave_reduce(acc[t][d]);
            if (lane == 0) sf[(t * 3 + d) * 4 + wave] = v;
        }
    __syncthreads();
    if (threadIdx.x < 15) {
        const float* p = &sf[threadIdx.x * 4];
        // series index s = (tbase + t)*3 + d == half*15 + threadIdx.x
        partials[(half * 15 + threadIdx.x) * PSTRIDE + b] = p[0] + p[1] + p[2] + p[3];
    }
}

__global__ void __launch_bounds__(1024) final_kernel(const float* __restrict__ partials,
                                                     int nblk, float* __restrict__ out) {
    __shared__ float ts[32];
    const int tid = threadIdx.x;
    const int srs = tid >> 5;      // 0..31, use <30; srs = t*3+d
    const int j = tid & 31;
    float v = 0.f;
    if (srs < 30) {
        const float* p = partials + (size_t)srs * PSTRIDE;
        for (int k = j; k < nblk; k += 32) v += p[k];
    }
#pragma unroll
    for (int off = 16; off > 0; off >>= 1) v += __shfl_down(v, off, 32);
    if (j == 0 && srs < 30) ts[srs] = v;
    __syncthreads();
    if (tid < OUT_SIZE) {
        float r;
        if (tid < 15) r = ts[tid];
        else if (tid == 15) r = ts[15] + ts[16] + ts[17];
        else if (tid == 16) r = ts[18] + ts[19] + ts[20];
        else r = ts[tid + 4];
        out[tid] = r;
    }
}

// ---------------- fallback path (R1, proven) ----------------

__global__ void zero_kernel_fb(unsigned int* __restrict__ hist, float* __restrict__ out) {
    int i = blockIdx.x * blockDim.x + threadIdx.x;
    int n4 = VOCAB / 4;
    if (i < n4) ((uint4*)hist)[i] = make_uint4(0u, 0u, 0u, 0u);
    if (i < OUT_SIZE) out[i] = 0.0f;
}

__global__ void hist_kernel_fb(const int* __restrict__ idx, unsigned int* __restrict__ hist, int n) {
    int i = blockIdx.x * blockDim.x + threadIdx.x;
    int i4 = i * 4;
    if (i4 + 3 < n) {
        int4 v = ((const int4*)idx)[i];
        atomicAdd(&hist[v.x], 1u);
        atomicAdd(&hist[v.y], 1u);
        atomicAdd(&hist[v.z], 1u);
        atomicAdd(&hist[v.w], 1u);
    } else {
        for (int j = i4; j < n; ++j) atomicAdd(&hist[idx[j]], 1u);
    }
}

__global__ void __launch_bounds__(256) reduce_kernel_fb(const float* __restrict__ W,
                                                        const unsigned int* __restrict__ hist,
                                                        float* __restrict__ out) {
    const int t = blockIdx.x / 64;
    const int b = blockIdx.x % 64;
    const float4* __restrict__ W4 = (const float4*)(W + (size_t)t * VOCAB * 3);
    const uint4* __restrict__ h4 = (const uint4*)hist;
    float a0 = 0.f, a1 = 0.f, a2 = 0.f;
    const int stride = 64 * 256;
    for (int g = b * 256 + (int)threadIdx.x; g < NGROUPS; g += stride) {
        uint4 c4 = h4[g];
        float4 w0 = W4[3 * g + 0];
        float4 w1 = W4[3 * g + 1];
        float4 w2 = W4[3 * g + 2];
        float c0 = (float)c4.x, c1 = (float)c4.y, c2 = (float)c4.z, c3 = (float)c4.w;
        a0 += c0 * w0.x + c1 * w0.w + c2 * w1.z + c3 * w2.y;
        a1 += c0 * w0.y + c1 * w1.x + c2 * w1.w + c3 * w2.z;
        a2 += c0 * w0.z + c1 * w1.y + c2 * w2.x + c3 * w2.w;
    }
    a0 = wave_reduce(a0);
    a1 = wave_reduce(a1);
    a2 = wave_reduce(a2);
    __shared__ float s[3][4];
    int wave = threadIdx.x >> 6;
    int lane = threadIdx.x & 63;
    if (lane == 0) { s[0][wave] = a0; s[1][wave] = a1; s[2][wave] = a2; }
    __syncthreads();
    if (threadIdx.x == 0) {
        float r0 = s[0][0] + s[0][1] + s[0][2] + s[0][3];
        float r1 = s[1][0] + s[1][1] + s[1][2] + s[1][3];
        float r2 = s[2][0] + s[2][1] + s[2][2] + s[2][3];
        if (t == 5) atomicAdd(&out[15], r0 + r1 + r2);
        else if (t == 6) atomicAdd(&out[16], r0 + r1 + r2);
        else {
            int base = (t < 5) ? t * 3 : 17 + (t - 7) * 3;
            atomicAdd(&out[base + 0], r0);
            atomicAdd(&out[base + 1], r1);
            atomicAdd(&out[base + 2], r2);
        }
    }
}

// ---------------- launch ----------------

extern "C" void kernel_launch(void* const* d_in, const int* in_sizes, int n_in,
                              void* d_out, int out_size, void* d_ws, size_t ws_size,
                              hipStream_t stream) {
    const int* eb_input = (const int*)d_in[0];
    // d_in[1] (eb_offset) irrelevant: sum over all bags == sum over all indices.
    const float* W = (const float*)d_in[2];
    float* out = (float*)d_out;
    int n_idx = in_sizes[0];

    const int nsrc = (n_idx + CHUNK - 1) / CHUNK;
    const size_t scat_bytes = (size_t)MAXSRC * CHUNK * 2;        // 8,388,608
    const size_t gs_off = scat_bytes;
    const size_t gs_bytes = (size_t)NBUCKETS * MAXSRC * 4;       // 1,003,520
    const size_t h0_off = gs_off + gs_bytes;
    const size_t hpart_bytes = (size_t)NBUCKETS * BPB * 2;       // 2,007,040
    const size_t h1_off = h0_off + hpart_bytes;
    const size_t part_off = (h1_off + hpart_bytes + 255) & ~(size_t)255;
    const size_t need = part_off + (size_t)30 * PSTRIDE * 4;     // ~13.6 MB

    if (nsrc <= MAXSRC && ws_size >= need) {
        unsigned short* scat = (unsigned short*)d_ws;
        unsigned int* gs32 = (unsigned int*)((char*)d_ws + gs_off);
        unsigned short* h0 = (unsigned short*)((char*)d_ws + h0_off);
        unsigned short* h1 = (unsigned short*)((char*)d_ws + h1_off);
        float* partials = (float*)((char*)d_ws + part_off);

        scatter_kernel<<<nsrc, 256, 0, stream>>>(eb_input, n_idx, scat, gs32);
        bucket_hist_kernel<<<NBUCKETS * 2, 512, 0, stream>>>(scat, gs32, nsrc, h0, h1);
        reduce_kernel<<<2 * RBLK_HALF, 256, 0, stream>>>(W, h0, h1, partials);
        final_kernel<<<1, 1024, 0, stream>>>(partials, RBLK_HALF, out);
    } else {
        unsigned int* hist = (unsigned int*)d_ws;
        int zblocks = (VOCAB / 4 + 255) / 256;
        zero_kernel_fb<<<zblocks, 256, 0, stream>>>(hist, out);
        int hthreads = (n_idx + 3) / 4;
        int hblocks = (hthreads + 255) / 256;
        hist_kernel_fb<<<hblocks, 256, 0, stream>>>(eb_input, hist, n_idx);
        reduce_kernel_fb<<<NUM_TABLES * 64, 256, 0, stream>>>(W, hist, out);
    }
}